// Round 1
// baseline (484.025 us; speedup 1.0000x reference)
//
#include <hip/hip_runtime.h>
#include <math.h>

// MHAttention: BS=8, D=256, L=1024, H=8, DK=32
// Round 1: correct fp32 implementation, flash-style tiled softmax (no S
// materialization), structured so the two GEMM cores (QK^T, AV) can be
// swapped to MFMA in later rounds.

constexpr int cBS = 8;
constexpr int cD  = 256;
constexpr int cL  = 1024;
constexpr int cH  = 8;
constexpr int cDK = 32;
#define EPS_F 1e-8f

// ---------------------------------------------------------------------------
// Kernel 1: project K (masked) and V (unmasked) into ws.
// kp[b][h][c][l] = mask[b][l] * sum_j Wk[h][c][j] * keys[b][h*DK+j][l]
// vp[b][h][c][l] =              sum_j Wv[h][c][j] * values[b][h*DK+j][l]
// grid: 1024 = (b:8, h:8, ltile:16 of 64), block 256.
// ---------------------------------------------------------------------------
__global__ __launch_bounds__(256, 4) void proj_kv_kernel(
    const float* __restrict__ keys, const float* __restrict__ values,
    const float* __restrict__ mask, const float* __restrict__ Wk,
    const float* __restrict__ Wv, float* __restrict__ kp,
    float* __restrict__ vp)
{
    __shared__ float xs[32][68];   // raw input tile [j][l], +pad
    __shared__ float wT[32][36];   // W transposed [j][c], 16B-aligned rows
    __shared__ float ms[64];

    const int t   = threadIdx.x;
    const int bid = blockIdx.x;
    const int lt  = bid & 15;
    const int h   = (bid >> 4) & 7;
    const int b   = bid >> 7;
    const int l0  = lt * 64;
    const int l   = t & 63;
    const int ig  = t >> 6;        // wave-uniform: 8 output channels/thread

    if (t < 64) ms[t] = mask[b * cL + l0 + t];

    for (int pass = 0; pass < 2; ++pass) {
        const float* __restrict__ x = (pass == 0) ? keys : values;
        const float* __restrict__ W = (pass == 0) ? Wk : Wv;
        float* __restrict__ dst     = (pass == 0) ? kp : vp;
        if (pass) __syncthreads();   // protect xs/wT reuse
        for (int idx = t; idx < 32 * 64; idx += 256) {
            int j = idx >> 6, ll = idx & 63;
            xs[j][ll] = x[(b * cD + h * cDK + j) * cL + l0 + ll];
        }
        for (int idx = t; idx < 1024; idx += 256) {
            int c = idx >> 5, j = idx & 31;
            wT[j][c] = W[(h * cDK + c) * cDK + j];
        }
        __syncthreads();
        float acc[8] = {0, 0, 0, 0, 0, 0, 0, 0};
        #pragma unroll
        for (int j = 0; j < 32; ++j) {
            float xv = xs[j][l];
            float4 w0 = *reinterpret_cast<const float4*>(&wT[j][ig * 8]);
            float4 w1 = *reinterpret_cast<const float4*>(&wT[j][ig * 8 + 4]);
            acc[0] += w0.x * xv; acc[1] += w0.y * xv;
            acc[2] += w0.z * xv; acc[3] += w0.w * xv;
            acc[4] += w1.x * xv; acc[5] += w1.y * xv;
            acc[6] += w1.z * xv; acc[7] += w1.w * xv;
        }
        float mk = (pass == 0) ? ms[l] : 1.0f;  // only K needs masking
        #pragma unroll
        for (int i = 0; i < 8; ++i) {
            int c = ig * 8 + i;
            dst[((b * cH + h) * cDK + c) * cL + l0 + l] = acc[i] * mk;
        }
    }
}

// ---------------------------------------------------------------------------
// Kernel 2: fused attention per (b, h, 64-row strip). Flash-style: per
// 64-wide e-tile compute s-tile -> row stats -> p-transform -> AV update.
// Writes val[b][h*DK+c][l] = (sum_e p*v) / (l_run + EPS).
// grid: 1024 = (b:8, h:8, strip:16), block 256.
// ---------------------------------------------------------------------------
__global__ __launch_bounds__(256, 3) void attn_kernel(
    const float* __restrict__ queries, const float* __restrict__ mask,
    const float* __restrict__ Wq, const float* __restrict__ kp,
    const float* __restrict__ vp, float* __restrict__ val)
{
    __shared__ float qs[32][68];      // q tile [c][r]
    __shared__ float ks[32][68];      // k tile [c][e]
    __shared__ float vs[32][68];      // v tile [c][e]
    __shared__ float ps[64][68];      // s/p tile [e][r]  (also temp for q stage)
    __shared__ float red[64 * 17];    // reductions (also temp for WqT)
    __shared__ float mrow[64], lrow[64], alph[64], ms[64];

    const int t     = threadIdx.x;
    const int bid   = blockIdx.x;
    const int strip = bid & 15;
    const int h     = (bid >> 4) & 7;
    const int b     = bid >> 7;
    const int r0    = strip * 64;

    float* psf = &ps[0][0];

    // ---- stage raw queries (ps as temp [j][r]) and WqT (red as temp) ----
    for (int idx = t; idx < 2048; idx += 256) {
        int j = idx >> 6, r = idx & 63;
        psf[j * 68 + r] = queries[(b * cD + h * cDK + j) * cL + r0 + r];
    }
    for (int idx = t; idx < 1024; idx += 256) {
        int c = idx >> 5, j = idx & 31;
        red[j * 32 + c] = Wq[(h * cDK + c) * cDK + j];
    }
    if (t < 64) { mrow[t] = -INFINITY; lrow[t] = 0.0f; }
    __syncthreads();

    // ---- project q in-block (no mask needed: absorbed by final out*m) ----
    {
        int r = t & 63, ig = t >> 6;
        float acc[8] = {0, 0, 0, 0, 0, 0, 0, 0};
        #pragma unroll
        for (int j = 0; j < 32; ++j) {
            float xv = psf[j * 68 + r];
            float4 w0 = *reinterpret_cast<const float4*>(&red[j * 32 + ig * 8]);
            float4 w1 = *reinterpret_cast<const float4*>(&red[j * 32 + ig * 8 + 4]);
            acc[0] += w0.x * xv; acc[1] += w0.y * xv;
            acc[2] += w0.z * xv; acc[3] += w0.w * xv;
            acc[4] += w1.x * xv; acc[5] += w1.y * xv;
            acc[6] += w1.z * xv; acc[7] += w1.w * xv;
        }
        #pragma unroll
        for (int i = 0; i < 8; ++i) qs[ig * 8 + i][r] = acc[i];
    }

    const int rg = t & 15;        // 4 rows: r = rg*4 + ri
    const int cg = t >> 4;        // 2a: 4 e's (cg*4+ej); 2b: 2 c's (cg*2+cj)
    float o[4][2] = {};
    const float* __restrict__ kpb = &kp[(b * cH + h) * cDK * cL];
    const float* __restrict__ vpb = &vp[(b * cH + h) * cDK * cL];

    for (int et = 0; et < 16; ++et) {
        const int e0 = et * 64;
        __syncthreads();  // A: previous 2b done / q-proj done
        for (int idx = t; idx < 512; idx += 256) {
            int c = idx >> 4, e4 = (idx & 15) * 4;
            *reinterpret_cast<float4*>(&ks[c][e4]) =
                *reinterpret_cast<const float4*>(&kpb[c * cL + e0 + e4]);
        }
        for (int idx = t; idx < 512; idx += 256) {
            int c = idx >> 4, e4 = (idx & 15) * 4;
            *reinterpret_cast<float4*>(&vs[c][e4]) =
                *reinterpret_cast<const float4*>(&vpb[c * cL + e0 + e4]);
        }
        if (t < 64) ms[t] = mask[b * cL + e0 + t];
        __syncthreads();  // B

        // ---- 2a: s-tile (64x64), 4x4 micro-tile per thread ----
        float sacc[4][4] = {};
        #pragma unroll
        for (int c = 0; c < 32; ++c) {
            float4 qv = *reinterpret_cast<const float4*>(&qs[c][rg * 4]);
            float4 kv = *reinterpret_cast<const float4*>(&ks[c][cg * 4]);
            float qa[4] = {qv.x, qv.y, qv.z, qv.w};
            float kb[4] = {kv.x, kv.y, kv.z, kv.w};
            #pragma unroll
            for (int ri = 0; ri < 4; ++ri)
                #pragma unroll
                for (int ej = 0; ej < 4; ++ej)
                    sacc[ri][ej] += qa[ri] * kb[ej];
        }
        #pragma unroll
        for (int ej = 0; ej < 4; ++ej) {
            int e = cg * 4 + ej;
            float4 pv = make_float4(sacc[0][ej], sacc[1][ej], sacc[2][ej], sacc[3][ej]);
            *reinterpret_cast<float4*>(&ps[e][rg * 4]) = pv;
        }
        #pragma unroll
        for (int ri = 0; ri < 4; ++ri) {
            float pm = fmaxf(fmaxf(sacc[ri][0], sacc[ri][1]),
                             fmaxf(sacc[ri][2], sacc[ri][3]));
            red[(rg * 4 + ri) * 17 + cg] = pm;
        }
        __syncthreads();  // C

        // ---- row stats: running max merge (masked e give s==0, matching
        //      reference max(logits*mask) semantics exactly) ----
        if (t < 64) {
            float tm = -INFINITY;
            #pragma unroll
            for (int k = 0; k < 16; ++k) tm = fmaxf(tm, red[t * 17 + k]);
            float mo = mrow[t];
            float mn = fmaxf(mo, tm);
            alph[t] = __expf(mo - mn);   // first tile: exp(-inf)=0, l was 0
            mrow[t] = mn;
        }
        __syncthreads();  // D

        // ---- transform s -> p = exp((s-m)*mask)*mask (exact ref formula) ----
        {
            int r = t & 63, eg2 = t >> 6;
            float mr = mrow[r];
            float partial = 0.0f;
            #pragma unroll
            for (int i = 0; i < 16; ++i) {
                int e = eg2 * 16 + i;
                float mke = ms[e];
                float z = (ps[e][r] - mr) * mke;   // z <= 0 always
                float p = __expf(z) * mke;
                ps[e][r] = p;
                partial += p;
            }
            red[r * 17 + eg2] = partial;
        }
        __syncthreads();  // E

        if (t < 64) {
            lrow[t] = lrow[t] * alph[t] +
                      red[t * 17] + red[t * 17 + 1] + red[t * 17 + 2] + red[t * 17 + 3];
        }

        // ---- 2b: o[r][c] += sum_e p[e][r] * v[c][e], with online rescale ----
        {
            float a_[4];
            #pragma unroll
            for (int ri = 0; ri < 4; ++ri) a_[ri] = alph[rg * 4 + ri];
            #pragma unroll
            for (int ri = 0; ri < 4; ++ri) { o[ri][0] *= a_[ri]; o[ri][1] *= a_[ri]; }
            const int c0 = cg * 2;
            #pragma unroll
            for (int e = 0; e < 64; e += 2) {
                float4 pA = *reinterpret_cast<const float4*>(&ps[e][rg * 4]);
                float4 pB = *reinterpret_cast<const float4*>(&ps[e + 1][rg * 4]);
                float2 v0 = *reinterpret_cast<const float2*>(&vs[c0][e]);
                float2 v1 = *reinterpret_cast<const float2*>(&vs[c0 + 1][e]);
                float pa[4] = {pA.x, pA.y, pA.z, pA.w};
                float pb[4] = {pB.x, pB.y, pB.z, pB.w};
                #pragma unroll
                for (int ri = 0; ri < 4; ++ri) {
                    o[ri][0] += pa[ri] * v0.x;
                    o[ri][0] += pb[ri] * v0.y;
                    o[ri][1] += pa[ri] * v1.x;
                    o[ri][1] += pb[ri] * v1.y;
                }
            }
        }
    }
    __syncthreads();

    // ---- epilogue: o / (l + EPS) -> val[b][h*DK+c][r0+r] ----
    {
        float il[4];
        #pragma unroll
        for (int ri = 0; ri < 4; ++ri) il[ri] = 1.0f / (lrow[rg * 4 + ri] + EPS_F);
        #pragma unroll
        for (int cj = 0; cj < 2; ++cj) {
            int c = cg * 2 + cj;
            float4 ov = make_float4(o[0][cj] * il[0], o[1][cj] * il[1],
                                    o[2][cj] * il[2], o[3][cj] * il[3]);
            *reinterpret_cast<float4*>(
                &val[((b * cH + h) * cDK + c) * cL + r0 + rg * 4]) = ov;
        }
    }
}

// ---------------------------------------------------------------------------
// Kernel 3: out[b][l][i] = mask[b][l] * (sum_j Wp[i][j]*val[b][j][l] + bp[i])
// grid: 256 = (b:8, ltile:32 of 32), block 256.
// Thread: igrp = t&31 -> i = igrp + 32k (k<8, strided for bank-free reads),
//         lg = t>>5 -> 4 l's.
// ---------------------------------------------------------------------------
__global__ __launch_bounds__(256, 2) void outproj_kernel(
    const float* __restrict__ val, const float* __restrict__ Wp,
    const float* __restrict__ bp, const float* __restrict__ mask,
    float* __restrict__ out)
{
    __shared__ float vt[256][36];    // val tile [j][l]
    __shared__ float wpT[32][260];   // Wp j-tile transposed [jj][i]

    const int t    = threadIdx.x;
    const int bid  = blockIdx.x;
    const int lt   = bid & 31;
    const int b    = bid >> 5;
    const int l0   = lt * 32;
    const int igrp = t & 31;
    const int lg   = t >> 5;

    for (int idx = t; idx < 2048; idx += 256) {
        int j = idx >> 3, l4 = (idx & 7) * 4;
        *reinterpret_cast<float4*>(&vt[j][l4]) =
            *reinterpret_cast<const float4*>(&val[(b * cD + j) * cL + l0 + l4]);
    }

    float acc[8][4] = {};
    for (int jt = 0; jt < 8; ++jt) {
        __syncthreads();
        {   // stage Wp[i][jt*32..+31] transposed; i = t
            const float4* src = reinterpret_cast<const float4*>(&Wp[t * cD + jt * 32]);
            #pragma unroll
            for (int q = 0; q < 8; ++q) {
                float4 w = src[q];
                wpT[q * 4 + 0][t] = w.x; wpT[q * 4 + 1][t] = w.y;
                wpT[q * 4 + 2][t] = w.z; wpT[q * 4 + 3][t] = w.w;
            }
        }
        __syncthreads();
        #pragma unroll 4
        for (int jj = 0; jj < 32; ++jj) {
            int j = jt * 32 + jj;
            float4 vv = *reinterpret_cast<const float4*>(&vt[j][lg * 4]);
            #pragma unroll
            for (int k = 0; k < 8; ++k) {
                float w = wpT[jj][igrp + 32 * k];
                acc[k][0] += w * vv.x; acc[k][1] += w * vv.y;
                acc[k][2] += w * vv.z; acc[k][3] += w * vv.w;
            }
        }
    }

    float mk[4];
    #pragma unroll
    for (int x = 0; x < 4; ++x) mk[x] = mask[b * cL + l0 + lg * 4 + x];
    #pragma unroll
    for (int k = 0; k < 8; ++k) {
        int i = igrp + 32 * k;
        float bpv = bp[i];
        #pragma unroll
        for (int x = 0; x < 4; ++x) {
            int l = l0 + lg * 4 + x;
            out[(b * cL + l) * cD + i] = (acc[k][x] + bpv) * mk[x];
        }
    }
}

// ---------------------------------------------------------------------------
extern "C" void kernel_launch(void* const* d_in, const int* in_sizes, int n_in,
                              void* d_out, int out_size, void* d_ws, size_t ws_size,
                              hipStream_t stream) {
    const float* queries = (const float*)d_in[0];
    const float* keys    = (const float*)d_in[1];
    const float* values  = (const float*)d_in[2];
    const float* mask    = (const float*)d_in[3];
    const float* Wq      = (const float*)d_in[4];
    const float* Wk      = (const float*)d_in[5];
    const float* Wv      = (const float*)d_in[6];
    const float* Wp      = (const float*)d_in[7];
    const float* bp      = (const float*)d_in[8];
    float* out = (float*)d_out;

    // ws layout (fp32): kp[2M] | vp[2M] | val[2M]  -> 24 MB total
    float* ws  = (float*)d_ws;
    float* kp  = ws;
    float* vp  = ws + 2097152;
    float* valb = ws + 4194304;

    proj_kv_kernel<<<dim3(1024), dim3(256), 0, stream>>>(keys, values, mask, Wk, Wv, kp, vp);
    attn_kernel<<<dim3(1024), dim3(256), 0, stream>>>(queries, mask, Wq, kp, vp, valb);
    outproj_kernel<<<dim3(256), dim3(256), 0, stream>>>(valb, Wp, bp, mask, out);
}

// Round 2
// 187.859 us; speedup vs baseline: 2.5765x; 2.5765x over previous
//
#include <hip/hip_runtime.h>
#include <math.h>

// MHAttention: BS=8, D=256, L=1024, H=8, DK=32
// Round 2: QK^T via split-bf16 MFMA (3x mfma_f32_16x16x32_bf16, fp32-grade
// precision), P*V via plain bf16 MFMA (computed as o^T = v * p^T so v's
// native [c][e] layout is the A operand). Softmax stats held in registers
// (rows are wave-private), 2 barriers per e-tile.

constexpr int cD  = 256;
constexpr int cL  = 1024;
constexpr int cH  = 8;
constexpr int cDK = 32;
#define EPS_F 1e-8f

typedef __attribute__((ext_vector_type(8))) short s8v;   // 8 bf16 = 4 VGPRs
typedef __attribute__((ext_vector_type(4))) float f4v;   // MFMA C/D

static __device__ __forceinline__ unsigned short f2bf(float x) {
    unsigned u = __float_as_uint(x);
    u += 0x7FFFu + ((u >> 16) & 1u);          // round-to-nearest-even
    return (unsigned short)(u >> 16);
}
static __device__ __forceinline__ float bf2f(unsigned short h) {
    return __uint_as_float(((unsigned)h) << 16);
}

// ---------------------------------------------------------------------------
// Kernel 1: K -> masked, split-bf16, layout [b][h][l][c] (B-frag staging
// layout for attn). V -> fp32 [b][h][c][l] (A-operand layout for P*V).
// grid 1024 = (b:8, h:8, lt:16 of 64 l), block 256.
// ---------------------------------------------------------------------------
__global__ __launch_bounds__(256, 4) void proj_kv_kernel(
    const float* __restrict__ keys, const float* __restrict__ values,
    const float* __restrict__ mask, const float* __restrict__ Wk,
    const float* __restrict__ Wv, unsigned short* __restrict__ kp_hi,
    unsigned short* __restrict__ kp_lo, float* __restrict__ vp)
{
    __shared__ __align__(16) float xs[32][68];
    __shared__ __align__(16) float wT[32][36];
    __shared__ float msl[64];

    const int t   = threadIdx.x;
    const int bid = blockIdx.x;
    const int lt  = bid & 15;
    const int h   = (bid >> 4) & 7;
    const int b   = bid >> 7;
    const int l0  = lt * 64;

    if (t < 64) msl[t] = mask[b * cL + l0 + t];

    // ---------------- K pass ----------------
    for (int idx = t; idx < 512; idx += 256) {
        int j = idx >> 4, l4 = (idx & 15) * 4;
        *reinterpret_cast<float4*>(&xs[j][l4]) =
            *reinterpret_cast<const float4*>(&keys[(b * cD + h * cDK + j) * cL + l0 + l4]);
    }
    for (int idx = t; idx < 1024; idx += 256) {
        int c = idx >> 5, j = idx & 31;
        wT[j][c] = Wk[(h * cDK + c) * cDK + j];
    }
    __syncthreads();
    {
        const int l = t & 63, ig = t >> 6;
        float acc[8] = {0, 0, 0, 0, 0, 0, 0, 0};
        #pragma unroll
        for (int j = 0; j < 32; ++j) {
            float xv = xs[j][l];
            float4 w0 = *reinterpret_cast<const float4*>(&wT[j][ig * 8]);
            float4 w1 = *reinterpret_cast<const float4*>(&wT[j][ig * 8 + 4]);
            acc[0] += w0.x * xv; acc[1] += w0.y * xv;
            acc[2] += w0.z * xv; acc[3] += w0.w * xv;
            acc[4] += w1.x * xv; acc[5] += w1.y * xv;
            acc[6] += w1.z * xv; acc[7] += w1.w * xv;
        }
        float mk = msl[l];
        s8v hv, lv;
        #pragma unroll
        for (int i = 0; i < 8; ++i) {
            float kv = acc[i] * mk;
            unsigned short hh = f2bf(kv);
            hv[i] = (short)hh;
            lv[i] = (short)f2bf(kv - bf2f(hh));
        }
        size_t off = (((size_t)(b * cH + h)) * cL + l0 + l) * cDK + ig * 8;
        *reinterpret_cast<s8v*>(&kp_hi[off]) = hv;
        *reinterpret_cast<s8v*>(&kp_lo[off]) = lv;
    }
    __syncthreads();

    // ---------------- V pass ----------------
    for (int idx = t; idx < 512; idx += 256) {
        int j = idx >> 4, l4 = (idx & 15) * 4;
        *reinterpret_cast<float4*>(&xs[j][l4]) =
            *reinterpret_cast<const float4*>(&values[(b * cD + h * cDK + j) * cL + l0 + l4]);
    }
    for (int idx = t; idx < 1024; idx += 256) {
        int c = idx >> 5, j = idx & 31;
        wT[j][c] = Wv[(h * cDK + c) * cDK + j];
    }
    __syncthreads();
    {
        const int l4 = (t & 15) * 4;
        const int c0 = (t >> 4) * 2;
        float a0[4] = {0, 0, 0, 0}, a1[4] = {0, 0, 0, 0};
        #pragma unroll
        for (int j = 0; j < 32; ++j) {
            float4 xv = *reinterpret_cast<const float4*>(&xs[j][l4]);
            float w0 = wT[j][c0], w1 = wT[j][c0 + 1];
            a0[0] += w0 * xv.x; a0[1] += w0 * xv.y; a0[2] += w0 * xv.z; a0[3] += w0 * xv.w;
            a1[0] += w1 * xv.x; a1[1] += w1 * xv.y; a1[2] += w1 * xv.z; a1[3] += w1 * xv.w;
        }
        size_t base = ((size_t)(b * cH + h)) * cDK;
        *reinterpret_cast<float4*>(&vp[(base + c0) * cL + l0 + l4]) =
            make_float4(a0[0], a0[1], a0[2], a0[3]);
        *reinterpret_cast<float4*>(&vp[(base + c0 + 1) * cL + l0 + l4]) =
            make_float4(a1[0], a1[1], a1[2], a1[3]);
    }
}

// ---------------------------------------------------------------------------
// Kernel 2: fused attention, MFMA. Block = (b, h, 64-row strip), 4 waves.
// Wave w owns rows [w*16, w*16+16): QK^T C-tiles, softmax stats (regs),
// p rows in LDS, and the o^T accumulator for those rows.
// grid 1024 = (b:8, h:8, strip:16), block 256.
// ---------------------------------------------------------------------------
__global__ __launch_bounds__(256, 4) void attn_kernel(
    const float* __restrict__ queries, const float* __restrict__ mask,
    const float* __restrict__ Wq, const unsigned short* __restrict__ kp_hi,
    const unsigned short* __restrict__ kp_lo, const float* __restrict__ vp,
    float* __restrict__ val)
{
    // strides in shorts: qs/ks rows 40 (80 B, 16-aligned), vs/pb rows 72 (144 B)
    __shared__ __align__(16) unsigned short qs_hi[64 * 40];
    __shared__ __align__(16) unsigned short qs_lo[64 * 40];
    __shared__ __align__(16) unsigned short ks_hi[64 * 40];
    __shared__ __align__(16) unsigned short ks_lo[64 * 40];
    __shared__ __align__(16) unsigned short vs_bf[32 * 72];
    __shared__ __align__(16) unsigned short pb[64 * 72];
    __shared__ float alph[64], ms[64], lpub[64];

    const int t     = threadIdx.x;
    const int bid   = blockIdx.x;
    const int strip = bid & 15;
    const int h     = (bid >> 4) & 7;
    const int b     = bid >> 7;
    const int r0    = strip * 64;
    const int lane  = t & 63;
    const int w     = t >> 6;            // wave id 0..3
    const int ln15  = lane & 15;
    const int lq    = lane >> 4;         // quad id 0..3

    // ---- stage raw queries (pb as fp32 temp [j][r]) + WqT (ks_hi temp) ----
    float* qtmp = reinterpret_cast<float*>(pb);      // [j][r] stride 68, 8704 B
    float* wqt  = reinterpret_cast<float*>(ks_hi);   // [j][c] stride 32, 4096 B
    for (int idx = t; idx < 2048; idx += 256) {
        int j = idx >> 6, r = idx & 63;
        qtmp[j * 68 + r] = queries[(b * cD + h * cDK + j) * cL + r0 + r];
    }
    for (int idx = t; idx < 1024; idx += 256) {
        int c = idx >> 5, j = idx & 31;
        wqt[j * 32 + c] = Wq[(h * cDK + c) * cDK + j];
    }
    __syncthreads();

    // ---- q projection (fp32), then split-bf16 into qs_hi/qs_lo [r][c] ----
    {
        const int r = t & 63, ig = t >> 6;
        float acc[8] = {0, 0, 0, 0, 0, 0, 0, 0};
        #pragma unroll
        for (int j = 0; j < 32; ++j) {
            float xv = qtmp[j * 68 + r];
            float4 w0 = *reinterpret_cast<const float4*>(&wqt[j * 32 + ig * 8]);
            float4 w1 = *reinterpret_cast<const float4*>(&wqt[j * 32 + ig * 8 + 4]);
            acc[0] += w0.x * xv; acc[1] += w0.y * xv;
            acc[2] += w0.z * xv; acc[3] += w0.w * xv;
            acc[4] += w1.x * xv; acc[5] += w1.y * xv;
            acc[6] += w1.z * xv; acc[7] += w1.w * xv;
        }
        s8v hv, lv;
        #pragma unroll
        for (int i = 0; i < 8; ++i) {
            unsigned short hh = f2bf(acc[i]);
            hv[i] = (short)hh;
            lv[i] = (short)f2bf(acc[i] - bf2f(hh));
        }
        *reinterpret_cast<s8v*>(&qs_hi[r * 40 + ig * 8]) = hv;
        *reinterpret_cast<s8v*>(&qs_lo[r * 40 + ig * 8]) = lv;
    }
    __syncthreads();

    // ---- A-frags for QK^T: q rows of this wave (persist across e-loop) ----
    const s8v qhA = *reinterpret_cast<const s8v*>(&qs_hi[(w * 16 + ln15) * 40 + lq * 8]);
    const s8v qlA = *reinterpret_cast<const s8v*>(&qs_lo[(w * 16 + ln15) * 40 + lq * 8]);

    f4v o0 = {0.f, 0.f, 0.f, 0.f}, o1 = {0.f, 0.f, 0.f, 0.f};
    float mo[4] = {-INFINITY, -INFINITY, -INFINITY, -INFINITY};
    float lr[4] = {0.f, 0.f, 0.f, 0.f};

    const size_t khbase = ((size_t)(b * cH + h)) * cL * cDK;   // shorts
    const float* __restrict__ vpb = vp + ((size_t)(b * cH + h)) * cDK * cL;

    for (int et = 0; et < 16; ++et) {
        const int e0 = et * 64;
        __syncthreads();   // protect ks/vs restage vs previous tile's reads

        {   // ks staging: thread -> (e = t>>2, q4 = t&3), fully coalesced
            int e = t >> 2, q4 = t & 3;
            size_t g = khbase + ((size_t)(e0 + e)) * cDK + q4 * 8;
            s8v kh = *reinterpret_cast<const s8v*>(&kp_hi[g]);
            s8v kl = *reinterpret_cast<const s8v*>(&kp_lo[g]);
            *reinterpret_cast<s8v*>(&ks_hi[e * 40 + q4 * 8]) = kh;
            *reinterpret_cast<s8v*>(&ks_lo[e * 40 + q4 * 8]) = kl;
        }
        {   // vs staging: thread -> (c = t>>3, e8 = (t&7)*8), fp32 -> bf16
            int c = t >> 3, e8 = (t & 7) * 8;
            float4 v0 = *reinterpret_cast<const float4*>(&vpb[c * cL + e0 + e8]);
            float4 v1 = *reinterpret_cast<const float4*>(&vpb[c * cL + e0 + e8 + 4]);
            s8v vv;
            vv[0] = (short)f2bf(v0.x); vv[1] = (short)f2bf(v0.y);
            vv[2] = (short)f2bf(v0.z); vv[3] = (short)f2bf(v0.w);
            vv[4] = (short)f2bf(v1.x); vv[5] = (short)f2bf(v1.y);
            vv[6] = (short)f2bf(v1.z); vv[7] = (short)f2bf(v1.w);
            *reinterpret_cast<s8v*>(&vs_bf[c * 72 + e8]) = vv;
        }
        if (t < 64) ms[t] = mask[b * cL + e0 + t];
        __syncthreads();   // publish staged tiles

        // ---- QK^T: 4 col-tiles, split-bf16 (hh + hl + lh) ----
        f4v s[4];
        #pragma unroll
        for (int tc = 0; tc < 4; ++tc) {
            const s8v kh = *reinterpret_cast<const s8v*>(&ks_hi[(tc * 16 + ln15) * 40 + lq * 8]);
            const s8v kl = *reinterpret_cast<const s8v*>(&ks_lo[(tc * 16 + ln15) * 40 + lq * 8]);
            f4v a = {0.f, 0.f, 0.f, 0.f};
            a = __builtin_amdgcn_mfma_f32_16x16x32_bf16(qhA, kh, a, 0, 0, 0);
            a = __builtin_amdgcn_mfma_f32_16x16x32_bf16(qhA, kl, a, 0, 0, 0);
            a = __builtin_amdgcn_mfma_f32_16x16x32_bf16(qlA, kh, a, 0, 0, 0);
            s[tc] = a;
        }

        // ---- softmax transform, all in registers + wave shuffles ----
        // lane holds s rows r = w*16 + lq*4 + reg, cols e = tc*16 + ln15
        float tm[4], a_[4], psum[4] = {0.f, 0.f, 0.f, 0.f};
        #pragma unroll
        for (int reg = 0; reg < 4; ++reg)
            tm[reg] = fmaxf(fmaxf(s[0][reg], s[1][reg]), fmaxf(s[2][reg], s[3][reg]));
        #pragma unroll
        for (int d = 1; d < 16; d <<= 1) {
            #pragma unroll
            for (int reg = 0; reg < 4; ++reg)
                tm[reg] = fmaxf(tm[reg], __shfl_xor(tm[reg], d));
        }
        #pragma unroll
        for (int reg = 0; reg < 4; ++reg) {
            float mn = fmaxf(mo[reg], tm[reg]);
            a_[reg]  = __expf(mo[reg] - mn);   // first tile: exp(-inf)=0
            mo[reg]  = mn;
        }
        if (ln15 == 0) {
            #pragma unroll
            for (int reg = 0; reg < 4; ++reg)
                alph[w * 16 + lq * 4 + reg] = a_[reg];
        }
        const int rbase = (w * 16 + lq * 4) * 72;
        #pragma unroll
        for (int tc = 0; tc < 4; ++tc) {
            float mk = ms[tc * 16 + ln15];
            int ecol = tc * 16 + ln15;
            #pragma unroll
            for (int reg = 0; reg < 4; ++reg) {
                float z = (s[tc][reg] - mo[reg]) * mk;   // z <= 0 always
                float p = __expf(z) * mk;
                psum[reg] += p;
                pb[rbase + reg * 72 + ecol] = f2bf(p);
            }
        }
        #pragma unroll
        for (int d = 1; d < 16; d <<= 1) {
            #pragma unroll
            for (int reg = 0; reg < 4; ++reg)
                psum[reg] += __shfl_xor(psum[reg], d);
        }
        #pragma unroll
        for (int reg = 0; reg < 4; ++reg)
            lr[reg] = lr[reg] * a_[reg] + psum[reg];

        // ---- P*V as o^T = v * p^T (wave-private rows: no barrier) ----
        {
            float al = alph[w * 16 + ln15];   // alpha for this lane's o column
            #pragma unroll
            for (int i = 0; i < 4; ++i) { o0[i] *= al; o1[i] *= al; }
            #pragma unroll
            for (int ks2 = 0; ks2 < 2; ++ks2) {
                int eoff = ks2 * 32 + lq * 8;
                const s8v pB  = *reinterpret_cast<const s8v*>(&pb[(w * 16 + ln15) * 72 + eoff]);
                const s8v vA0 = *reinterpret_cast<const s8v*>(&vs_bf[ln15 * 72 + eoff]);
                const s8v vA1 = *reinterpret_cast<const s8v*>(&vs_bf[(16 + ln15) * 72 + eoff]);
                o0 = __builtin_amdgcn_mfma_f32_16x16x32_bf16(vA0, pB, o0, 0, 0, 0);
                o1 = __builtin_amdgcn_mfma_f32_16x16x32_bf16(vA1, pB, o1, 0, 0, 0);
            }
        }
    }

    // ---- epilogue: publish l (wave-private rows), divide, store ----
    if (ln15 == 0) {
        #pragma unroll
        for (int reg = 0; reg < 4; ++reg)
            lpub[w * 16 + lq * 4 + reg] = lr[reg];
    }
    float linv = 1.0f / (lpub[w * 16 + ln15] + EPS_F);
    const int rg = r0 + w * 16 + ln15;
    const size_t vbase = ((size_t)(b * cH + h)) * cDK;
    #pragma unroll
    for (int reg = 0; reg < 4; ++reg) {
        int cl = lq * 4 + reg;
        val[(vbase + cl) * cL + rg]      = o0[reg] * linv;
        val[(vbase + 16 + cl) * cL + rg] = o1[reg] * linv;
    }
}

// ---------------------------------------------------------------------------
// Kernel 3: out[b][l][i] = mask[b][l] * (sum_j Wp[i][j]*val[b][j][l] + bp[i])
// grid 256 = (b:8, lt:32 of 32 l), block 256. (unchanged from round 1)
// ---------------------------------------------------------------------------
__global__ __launch_bounds__(256, 2) void outproj_kernel(
    const float* __restrict__ val, const float* __restrict__ Wp,
    const float* __restrict__ bp, const float* __restrict__ mask,
    float* __restrict__ out)
{
    __shared__ float vt[256][36];
    __shared__ float wpT[32][260];

    const int t    = threadIdx.x;
    const int bid  = blockIdx.x;
    const int lt   = bid & 31;
    const int b    = bid >> 5;
    const int l0   = lt * 32;
    const int igrp = t & 31;
    const int lg   = t >> 5;

    for (int idx = t; idx < 2048; idx += 256) {
        int j = idx >> 3, l4 = (idx & 7) * 4;
        *reinterpret_cast<float4*>(&vt[j][l4]) =
            *reinterpret_cast<const float4*>(&val[(b * cD + j) * cL + l0 + l4]);
    }

    float acc[8][4] = {};
    for (int jt = 0; jt < 8; ++jt) {
        __syncthreads();
        {
            const float4* src = reinterpret_cast<const float4*>(&Wp[t * cD + jt * 32]);
            #pragma unroll
            for (int q = 0; q < 8; ++q) {
                float4 wv = src[q];
                wpT[q * 4 + 0][t] = wv.x; wpT[q * 4 + 1][t] = wv.y;
                wpT[q * 4 + 2][t] = wv.z; wpT[q * 4 + 3][t] = wv.w;
            }
        }
        __syncthreads();
        #pragma unroll 4
        for (int jj = 0; jj < 32; ++jj) {
            int j = jt * 32 + jj;
            float4 vv = *reinterpret_cast<const float4*>(&vt[j][lg * 4]);
            #pragma unroll
            for (int k = 0; k < 8; ++k) {
                float wv = wpT[jj][igrp + 32 * k];
                acc[k][0] += wv * vv.x; acc[k][1] += wv * vv.y;
                acc[k][2] += wv * vv.z; acc[k][3] += wv * vv.w;
            }
        }
    }

    float mk[4];
    #pragma unroll
    for (int x = 0; x < 4; ++x) mk[x] = mask[b * cL + l0 + lg * 4 + x];
    #pragma unroll
    for (int k = 0; k < 8; ++k) {
        int i = igrp + 32 * k;
        float bpv = bp[i];
        #pragma unroll
        for (int x = 0; x < 4; ++x) {
            int l = l0 + lg * 4 + x;
            out[(b * cL + l) * cD + i] = (acc[k][x] + bpv) * mk[x];
        }
    }
}

// ---------------------------------------------------------------------------
extern "C" void kernel_launch(void* const* d_in, const int* in_sizes, int n_in,
                              void* d_out, int out_size, void* d_ws, size_t ws_size,
                              hipStream_t stream) {
    const float* queries = (const float*)d_in[0];
    const float* keys    = (const float*)d_in[1];
    const float* values  = (const float*)d_in[2];
    const float* mask    = (const float*)d_in[3];
    const float* Wq      = (const float*)d_in[4];
    const float* Wk      = (const float*)d_in[5];
    const float* Wv      = (const float*)d_in[6];
    const float* Wp      = (const float*)d_in[7];
    const float* bp      = (const float*)d_in[8];
    float* out = (float*)d_out;

    // ws: kp_hi 4MB | kp_lo 4MB | vp 8MB | val 8MB  (24 MB)
    char* wsb = (char*)d_ws;
    unsigned short* kp_hi = (unsigned short*)(wsb);
    unsigned short* kp_lo = (unsigned short*)(wsb + (4u << 20));
    float* vp   = (float*)(wsb + (8u << 20));
    float* valb = (float*)(wsb + (16u << 20));

    proj_kv_kernel<<<dim3(1024), dim3(256), 0, stream>>>(keys, values, mask, Wk, Wv,
                                                         kp_hi, kp_lo, vp);
    attn_kernel<<<dim3(1024), dim3(256), 0, stream>>>(queries, mask, Wq,
                                                      kp_hi, kp_lo, vp, valb);
    outproj_kernel<<<dim3(256), dim3(256), 0, stream>>>(valb, Wp, bp, mask, out);
}

// Round 3
// 144.958 us; speedup vs baseline: 3.3391x; 1.2960x over previous
//
#include <hip/hip_runtime.h>
#include <math.h>

// MHAttention: BS=8, D=256, L=1024, H=8, DK=32
// Round 3: S^T = K.Q^T so softmax rows are lane-scalar (stats in regs, 2
// shuffles instead of 16+); p round-trips LDS wave-privately (no barrier);
// double-buffered K/V staging, 1 barrier per e-tile; V carried bf16;
// out-projection as bf16 MFMA with 512 blocks.

constexpr int cD  = 256;
constexpr int cL  = 1024;
constexpr int cH  = 8;
constexpr int cDK = 32;

typedef __attribute__((ext_vector_type(8))) short s8v;   // 8 bf16 = 4 VGPRs
typedef __attribute__((ext_vector_type(4))) float f4v;   // MFMA C/D
typedef unsigned int u32;
typedef unsigned short u16;

static __device__ __forceinline__ u32 rne_hi(float x) {
    u32 u = __float_as_uint(x);
    return u + 0x7fffu + ((u >> 16) & 1u);       // bf16 RNE in high half
}
static __device__ __forceinline__ u32 pack_bf2(float a, float b) {
    // low short = bf16(a), high short = bf16(b)
    return __builtin_amdgcn_perm(rne_hi(b), rne_hi(a), 0x07060302u);
}
static __device__ __forceinline__ u16 f2bf(float x) { return (u16)(rne_hi(x) >> 16); }
static __device__ __forceinline__ float bf2f(u16 h) { return __uint_as_float(((u32)h) << 16); }

// ---------------------------------------------------------------------------
// Kernel 1: K -> masked split-bf16 [b][h][l][c] (A-frag staging layout);
// V -> bf16 [b][h][c][l]. grid 1024 = (b:8, h:8, lt:16 of 64 l), block 256.
// ---------------------------------------------------------------------------
__global__ __launch_bounds__(256, 4) void proj_kv_kernel(
    const float* __restrict__ keys, const float* __restrict__ values,
    const float* __restrict__ mask, const float* __restrict__ Wk,
    const float* __restrict__ Wv, u16* __restrict__ kp_hi,
    u16* __restrict__ kp_lo, u16* __restrict__ vp_bf)
{
    __shared__ __align__(16) float xs[32][68];
    __shared__ __align__(16) float wT[32][36];
    __shared__ float msl[64];

    const int t   = threadIdx.x;
    const int bid = blockIdx.x;
    const int lt  = bid & 15;
    const int h   = (bid >> 4) & 7;
    const int b   = bid >> 7;
    const int l0  = lt * 64;

    if (t < 64) msl[t] = mask[b * cL + l0 + t];

    // ---------------- K pass ----------------
    for (int idx = t; idx < 512; idx += 256) {
        int j = idx >> 4, l4 = (idx & 15) * 4;
        *reinterpret_cast<float4*>(&xs[j][l4]) =
            *reinterpret_cast<const float4*>(&keys[(b * cD + h * cDK + j) * cL + l0 + l4]);
    }
    for (int idx = t; idx < 1024; idx += 256) {
        int c = idx >> 5, j = idx & 31;
        wT[j][c] = Wk[(h * cDK + c) * cDK + j];
    }
    __syncthreads();
    {
        const int l = t & 63, ig = t >> 6;
        float acc[8] = {0, 0, 0, 0, 0, 0, 0, 0};
        #pragma unroll
        for (int j = 0; j < 32; ++j) {
            float xv = xs[j][l];
            float4 w0 = *reinterpret_cast<const float4*>(&wT[j][ig * 8]);
            float4 w1 = *reinterpret_cast<const float4*>(&wT[j][ig * 8 + 4]);
            acc[0] += w0.x * xv; acc[1] += w0.y * xv;
            acc[2] += w0.z * xv; acc[3] += w0.w * xv;
            acc[4] += w1.x * xv; acc[5] += w1.y * xv;
            acc[6] += w1.z * xv; acc[7] += w1.w * xv;
        }
        float mk = msl[l];
        s8v hv, lv;
        #pragma unroll
        for (int i = 0; i < 8; ++i) {
            float kv = acc[i] * mk;
            u16 hh = f2bf(kv);
            hv[i] = (short)hh;
            lv[i] = (short)f2bf(kv - bf2f(hh));
        }
        size_t off = (((size_t)(b * cH + h)) * cL + l0 + l) * cDK + ig * 8;
        *reinterpret_cast<s8v*>(&kp_hi[off]) = hv;
        *reinterpret_cast<s8v*>(&kp_lo[off]) = lv;
    }
    __syncthreads();

    // ---------------- V pass ----------------
    for (int idx = t; idx < 512; idx += 256) {
        int j = idx >> 4, l4 = (idx & 15) * 4;
        *reinterpret_cast<float4*>(&xs[j][l4]) =
            *reinterpret_cast<const float4*>(&values[(b * cD + h * cDK + j) * cL + l0 + l4]);
    }
    for (int idx = t; idx < 1024; idx += 256) {
        int c = idx >> 5, j = idx & 31;
        wT[j][c] = Wv[(h * cDK + c) * cDK + j];
    }
    __syncthreads();
    {
        const int l4 = (t & 15) * 4;
        const int c0 = (t >> 4) * 2;
        float a0[4] = {0, 0, 0, 0}, a1[4] = {0, 0, 0, 0};
        #pragma unroll
        for (int j = 0; j < 32; ++j) {
            float4 xv = *reinterpret_cast<const float4*>(&xs[j][l4]);
            float w0 = wT[j][c0], w1 = wT[j][c0 + 1];
            a0[0] += w0 * xv.x; a0[1] += w0 * xv.y; a0[2] += w0 * xv.z; a0[3] += w0 * xv.w;
            a1[0] += w1 * xv.x; a1[1] += w1 * xv.y; a1[2] += w1 * xv.z; a1[3] += w1 * xv.w;
        }
        size_t base = ((size_t)(b * cH + h)) * cDK;
        uint2 v0 = make_uint2(pack_bf2(a0[0], a0[1]), pack_bf2(a0[2], a0[3]));
        uint2 v1 = make_uint2(pack_bf2(a1[0], a1[1]), pack_bf2(a1[2], a1[3]));
        *reinterpret_cast<uint2*>(&vp_bf[(base + c0) * cL + l0 + l4])     = v0;
        *reinterpret_cast<uint2*>(&vp_bf[(base + c0 + 1) * cL + l0 + l4]) = v1;
    }
}

// ---------------------------------------------------------------------------
// Kernel 2: fused attention. Block = (b, h, 64-row strip), 4 waves; wave w
// owns rows r = w*16 + ln15 (one row per lane, end-to-end).
// grid 1024 = (b:8, h:8, strip:16), block 256.
// ---------------------------------------------------------------------------
__global__ __launch_bounds__(256, 3) void attn_kernel(
    const float* __restrict__ queries, const float* __restrict__ mask,
    const float* __restrict__ Wq, const u16* __restrict__ kp_hi,
    const u16* __restrict__ kp_lo, const u16* __restrict__ vp_bf,
    u16* __restrict__ val_bf)
{
    __shared__ __align__(16) u16 ksbuf[2][2][2048];   // [buf][hi/lo][64e][32c]
    __shared__ __align__(16) u16 qsb[2][2048];        // [hi/lo][64r][32c]
    __shared__ __align__(16) u16 vsbuf[2][2304];      // [buf][32c][72e-pad]
    __shared__ __align__(16) u32 pb32[2304];          // [64r][36 e-pair-pad]
    __shared__ __align__(16) float msbuf[2][64];

    const int t     = threadIdx.x;
    const int bid   = blockIdx.x;
    const int strip = bid & 15;
    const int h     = (bid >> 4) & 7;
    const int b     = bid >> 7;
    const int r0    = strip * 64;
    const int lane  = t & 63;
    const int w     = t >> 6;
    const int ln15  = lane & 15;
    const int lq    = lane >> 4;

    // ---- prologue: stage raw q + WqT into ksbuf-aliased scratch ----
    float* qtmp = reinterpret_cast<float*>(&ksbuf[0][0][0]);                 // [32][68]
    float* wqt  = reinterpret_cast<float*>((char*)&ksbuf[0][0][0] + 8704);   // [32][32]
    {
        int j = t >> 3, f8 = (t & 7) * 8;
        const float* src = &queries[(b * cD + h * cDK + j) * cL + r0 + f8];
        float4 v0 = *reinterpret_cast<const float4*>(src);
        float4 v1 = *reinterpret_cast<const float4*>(src + 4);
        *reinterpret_cast<float4*>(&qtmp[j * 68 + f8])     = v0;
        *reinterpret_cast<float4*>(&qtmp[j * 68 + f8 + 4]) = v1;
    }
    {
        int c = t >> 3, j4 = (t & 7) * 4;
        float4 wv = *reinterpret_cast<const float4*>(&Wq[(h * cDK + c) * cDK + j4]);
        wqt[(j4 + 0) * 32 + c] = wv.x; wqt[(j4 + 1) * 32 + c] = wv.y;
        wqt[(j4 + 2) * 32 + c] = wv.z; wqt[(j4 + 3) * 32 + c] = wv.w;
    }
    __syncthreads();

    // ---- q projection (fp32) -> split-bf16 qsb[hi/lo][r][c] ----
    {
        float acc[8] = {0, 0, 0, 0, 0, 0, 0, 0};
        #pragma unroll
        for (int j = 0; j < 32; ++j) {
            float xv = qtmp[j * 68 + lane];
            float4 w0 = *reinterpret_cast<const float4*>(&wqt[j * 32 + w * 8]);
            float4 w1 = *reinterpret_cast<const float4*>(&wqt[j * 32 + w * 8 + 4]);
            acc[0] += w0.x * xv; acc[1] += w0.y * xv;
            acc[2] += w0.z * xv; acc[3] += w0.w * xv;
            acc[4] += w1.x * xv; acc[5] += w1.y * xv;
            acc[6] += w1.z * xv; acc[7] += w1.w * xv;
        }
        s8v hv, lv;
        #pragma unroll
        for (int i = 0; i < 8; ++i) {
            u16 hh = f2bf(acc[i]);
            hv[i] = (short)hh;
            lv[i] = (short)f2bf(acc[i] - bf2f(hh));
        }
        *reinterpret_cast<s8v*>(&qsb[0][lane * 32 + w * 8]) = hv;
        *reinterpret_cast<s8v*>(&qsb[1][lane * 32 + w * 8]) = lv;
    }
    __syncthreads();   // qtmp/wqt dead; qsb published

    const size_t kvbase = ((size_t)(b * cH + h)) * 32768;   // shorts
    const int se = t >> 2, sc = (t & 3) * 8;                // ks staging coords
    const int vc = t >> 3, ve = (t & 7) * 8;                // vs staging coords

    // ---- stage tile 0 into buf 0 ----
    {
        s8v kh = *reinterpret_cast<const s8v*>(&kp_hi[kvbase + se * 32 + sc]);
        s8v kl = *reinterpret_cast<const s8v*>(&kp_lo[kvbase + se * 32 + sc]);
        *reinterpret_cast<s8v*>(&ksbuf[0][0][se * 32 + sc]) = kh;
        *reinterpret_cast<s8v*>(&ksbuf[0][1][se * 32 + sc]) = kl;
        s8v vv = *reinterpret_cast<const s8v*>(&vp_bf[kvbase + vc * 1024 + ve]);
        *reinterpret_cast<s8v*>(&vsbuf[0][vc * 72 + ve]) = vv;
        if (t < 64) msbuf[0][t] = mask[b * cL + t];
    }

    // ---- persistent B-frags: q rows of this wave ----
    const s8v qh = *reinterpret_cast<const s8v*>(&qsb[0][(w * 16 + ln15) * 32 + lq * 8]);
    const s8v ql = *reinterpret_cast<const s8v*>(&qsb[1][(w * 16 + ln15) * 32 + lq * 8]);

    f4v o0 = {0.f, 0.f, 0.f, 0.f}, o1 = {0.f, 0.f, 0.f, 0.f};
    float mo = -INFINITY, lr = 0.f;
    const int pbrow = (w * 16 + ln15) * 36;
    const int ksoff = ln15 * 32 + lq * 8;
    const int vsoff = ln15 * 72 + lq * 8;

    for (int et = 0; et < 16; ++et) {
        __syncthreads();        // tile et visible in buf pp
        const int pp = et & 1;
        const bool pre = (et < 15);
        s8v khp, klp, vvp; float msp = 0.f;
        if (pre) {              // early global loads for tile et+1
            const int e0n = (et + 1) * 64;
            khp = *reinterpret_cast<const s8v*>(&kp_hi[kvbase + (e0n + se) * 32 + sc]);
            klp = *reinterpret_cast<const s8v*>(&kp_lo[kvbase + (e0n + se) * 32 + sc]);
            vvp = *reinterpret_cast<const s8v*>(&vp_bf[kvbase + vc * 1024 + e0n + ve]);
            if (t < 64) msp = mask[b * cL + e0n + t];
        }

        // ---- S^T tiles: D[e][r] = K[e][c] x Q^T, split-bf16 ----
        f4v sA[4];
        #pragma unroll
        for (int es = 0; es < 4; ++es) {
            const s8v kh = *reinterpret_cast<const s8v*>(&ksbuf[pp][0][es * 512 + ksoff]);
            const s8v kl = *reinterpret_cast<const s8v*>(&ksbuf[pp][1][es * 512 + ksoff]);
            f4v a = {0.f, 0.f, 0.f, 0.f};
            a = __builtin_amdgcn_mfma_f32_16x16x32_bf16(kh, qh, a, 0, 0, 0);
            a = __builtin_amdgcn_mfma_f32_16x16x32_bf16(kl, qh, a, 0, 0, 0);
            a = __builtin_amdgcn_mfma_f32_16x16x32_bf16(kh, ql, a, 0, 0, 0);
            sA[es] = a;
        }

        // ---- softmax: lane owns one row r = w*16+ln15 (scalar stats) ----
        float tm = fmaxf(fmaxf(fmaxf(sA[0][0], sA[0][1]), fmaxf(sA[0][2], sA[0][3])),
                   fmaxf(fmaxf(fmaxf(sA[1][0], sA[1][1]), fmaxf(sA[1][2], sA[1][3])),
                   fmaxf(fmaxf(fmaxf(sA[2][0], sA[2][1]), fmaxf(sA[2][2], sA[2][3])),
                         fmaxf(fmaxf(sA[3][0], sA[3][1]), fmaxf(sA[3][2], sA[3][3])))));
        tm = fmaxf(tm, __shfl_xor(tm, 16));
        tm = fmaxf(tm, __shfl_xor(tm, 32));
        const float mn = fmaxf(mo, tm);
        const float al = __expf(mo - mn);     // first tile: exp(-inf) = 0
        mo = mn;
        o0[0] *= al; o0[1] *= al; o0[2] *= al; o0[3] *= al;
        o1[0] *= al; o1[1] *= al; o1[2] *= al; o1[3] *= al;

        float ps = 0.f;
        #pragma unroll
        for (int es = 0; es < 4; ++es) {
            float4 mk4 = *reinterpret_cast<const float4*>(&msbuf[pp][es * 16 + lq * 4]);
            float p0 = __expf((sA[es][0] - mn) * mk4.x) * mk4.x;
            float p1 = __expf((sA[es][1] - mn) * mk4.y) * mk4.y;
            float p2 = __expf((sA[es][2] - mn) * mk4.z) * mk4.z;
            float p3 = __expf((sA[es][3] - mn) * mk4.w) * mk4.w;
            ps += (p0 + p1) + (p2 + p3);
            uint2 pk = make_uint2(pack_bf2(p0, p1), pack_bf2(p2, p3));
            *reinterpret_cast<uint2*>(&pb32[pbrow + es * 8 + lq * 2]) = pk;  // wave-private
        }
        ps += __shfl_xor(ps, 16);
        ps += __shfl_xor(ps, 32);
        lr = lr * al + ps;

        // ---- PV: o^T[c][r] += V[c][e] x P^T[e][r] (no barrier needed) ----
        #pragma unroll
        for (int ch = 0; ch < 2; ++ch) {
            s8v pB  = *reinterpret_cast<const s8v*>(
                          reinterpret_cast<const u16*>(&pb32[pbrow + ch * 16 + lq * 4]));
            s8v vA0 = *reinterpret_cast<const s8v*>(&vsbuf[pp][vsoff + ch * 32]);
            s8v vA1 = *reinterpret_cast<const s8v*>(&vsbuf[pp][vsoff + ch * 32 + 1152]);
            o0 = __builtin_amdgcn_mfma_f32_16x16x32_bf16(vA0, pB, o0, 0, 0, 0);
            o1 = __builtin_amdgcn_mfma_f32_16x16x32_bf16(vA1, pB, o1, 0, 0, 0);
        }

        // ---- late LDS writes: publish tile et+1 into buf pp^1 ----
        if (pre) {
            const int bn = pp ^ 1;
            *reinterpret_cast<s8v*>(&ksbuf[bn][0][se * 32 + sc]) = khp;
            *reinterpret_cast<s8v*>(&ksbuf[bn][1][se * 32 + sc]) = klp;
            *reinterpret_cast<s8v*>(&vsbuf[bn][vc * 72 + ve]) = vvp;
            if (t < 64) msbuf[bn][t] = msp;
        }
    }

    // ---- epilogue: val_bf[b][l=r][h*32+c] = bf16(o / (l + eps)) ----
    {
        const float linv = 1.0f / (lr + 1e-8f);
        const size_t obase = ((size_t)(b * cL + r0 + w * 16 + ln15)) * cD + h * cDK;
        uint2 q0 = make_uint2(pack_bf2(o0[0] * linv, o0[1] * linv),
                              pack_bf2(o0[2] * linv, o0[3] * linv));
        uint2 q1 = make_uint2(pack_bf2(o1[0] * linv, o1[1] * linv),
                              pack_bf2(o1[2] * linv, o1[3] * linv));
        *reinterpret_cast<uint2*>(&val_bf[obase + lq * 4])      = q0;
        *reinterpret_cast<uint2*>(&val_bf[obase + 16 + lq * 4]) = q1;
    }
}

// ---------------------------------------------------------------------------
// Kernel 3: out[b][l][i] = mask[b][l] * (sum_j Wp[i][j]*val[b][l][j] + bp[i])
// bf16 MFMA. grid 512 = (b:8, lt:16 of 64 l, it:4 of 64 i), block 256.
// ---------------------------------------------------------------------------
__global__ __launch_bounds__(256, 2) void outproj_kernel(
    const u16* __restrict__ val_bf, const float* __restrict__ Wp,
    const float* __restrict__ bp, const float* __restrict__ mask,
    float* __restrict__ out)
{
    __shared__ __align__(16) u16 vt[64 * 264];    // [64 l][264 j-pad]
    __shared__ __align__(16) u16 wpb[64 * 264];   // [64 i][264 j-pad]
    __shared__ float mrow[64];

    const int t    = threadIdx.x;
    const int bid  = blockIdx.x;
    const int it   = bid & 3;
    const int lt   = (bid >> 2) & 15;
    const int b    = bid >> 6;
    const int l0   = lt * 64, i0 = it * 64;
    const int lane = t & 63, w = t >> 6, ln15 = lane & 15, lq = lane >> 4;

    {   // stage val tile (bf16 copy)
        int row = t >> 2, seg = (t & 3) * 64;
        const u16* src = &val_bf[((size_t)(b * cL + l0 + row)) * cD + seg];
        #pragma unroll
        for (int k = 0; k < 4; ++k) {
            s8v a0 = *reinterpret_cast<const s8v*>(src + k * 16);
            s8v a1 = *reinterpret_cast<const s8v*>(src + k * 16 + 8);
            *reinterpret_cast<s8v*>(&vt[row * 264 + seg + k * 16])     = a0;
            *reinterpret_cast<s8v*>(&vt[row * 264 + seg + k * 16 + 8]) = a1;
        }
    }
    {   // stage Wp tile (fp32 -> bf16)
        int row = t >> 2, seg = (t & 3) * 64;
        const float* src = &Wp[((size_t)(i0 + row)) * cD + seg];
        #pragma unroll
        for (int k = 0; k < 8; ++k) {
            float4 f0 = *reinterpret_cast<const float4*>(src + k * 8);
            float4 f1 = *reinterpret_cast<const float4*>(src + k * 8 + 4);
            uint4 pk = make_uint4(pack_bf2(f0.x, f0.y), pack_bf2(f0.z, f0.w),
                                  pack_bf2(f1.x, f1.y), pack_bf2(f1.z, f1.w));
            *reinterpret_cast<uint4*>(&wpb[row * 264 + seg + k * 8]) = pk;
        }
    }
    if (t < 64) mrow[t] = mask[b * cL + l0 + t];
    __syncthreads();

    f4v acc[4] = {{0.f, 0.f, 0.f, 0.f}, {0.f, 0.f, 0.f, 0.f},
                  {0.f, 0.f, 0.f, 0.f}, {0.f, 0.f, 0.f, 0.f}};
    #pragma unroll
    for (int kc = 0; kc < 8; ++kc) {
        s8v aA = *reinterpret_cast<const s8v*>(&vt[(w * 16 + ln15) * 264 + kc * 32 + lq * 8]);
        #pragma unroll
        for (int ti = 0; ti < 4; ++ti) {
            s8v bB = *reinterpret_cast<const s8v*>(&wpb[(ti * 16 + ln15) * 264 + kc * 32 + lq * 8]);
            acc[ti] = __builtin_amdgcn_mfma_f32_16x16x32_bf16(aA, bB, acc[ti], 0, 0, 0);
        }
    }

    float mk[4];
    #pragma unroll
    for (int rg = 0; rg < 4; ++rg) mk[rg] = mrow[w * 16 + lq * 4 + rg];
    #pragma unroll
    for (int ti = 0; ti < 4; ++ti) {
        float bpv = bp[i0 + ti * 16 + ln15];
        #pragma unroll
        for (int rg = 0; rg < 4; ++rg) {
            int l = l0 + w * 16 + lq * 4 + rg;
            out[((size_t)(b * cL + l)) * cD + i0 + ti * 16 + ln15] =
                (acc[ti][rg] + bpv) * mk[rg];
        }
    }
}

// ---------------------------------------------------------------------------
extern "C" void kernel_launch(void* const* d_in, const int* in_sizes, int n_in,
                              void* d_out, int out_size, void* d_ws, size_t ws_size,
                              hipStream_t stream) {
    const float* queries = (const float*)d_in[0];
    const float* keys    = (const float*)d_in[1];
    const float* values  = (const float*)d_in[2];
    const float* mask    = (const float*)d_in[3];
    const float* Wq      = (const float*)d_in[4];
    const float* Wk      = (const float*)d_in[5];
    const float* Wv      = (const float*)d_in[6];
    const float* Wp      = (const float*)d_in[7];
    const float* bp      = (const float*)d_in[8];
    float* out = (float*)d_out;

    // ws: kp_hi 4MB | kp_lo 4MB | vp_bf 4MB | val_bf 4MB  (16 MB)
    char* wsb = (char*)d_ws;
    u16* kp_hi  = (u16*)(wsb);
    u16* kp_lo  = (u16*)(wsb + (4u << 20));
    u16* vp_bf  = (u16*)(wsb + (8u << 20));
    u16* val_bf = (u16*)(wsb + (12u << 20));

    proj_kv_kernel<<<dim3(1024), dim3(256), 0, stream>>>(keys, values, mask, Wk, Wv,
                                                         kp_hi, kp_lo, vp_bf);
    attn_kernel<<<dim3(1024), dim3(256), 0, stream>>>(queries, mask, Wq,
                                                      kp_hi, kp_lo, vp_bf, val_bf);
    outproj_kernel<<<dim3(512), dim3(256), 0, stream>>>(val_bf, Wp, bp, mask, out);
}

// Round 4
// 131.692 us; speedup vs baseline: 3.6754x; 1.1007x over previous
//
#include <hip/hip_runtime.h>
#include <math.h>

// MHAttention: BS=8, D=256, L=1024, H=8, DK=32
// Round 4: full fp16 pipeline (error budget analysis: delta_s ~ 0.004 abs,
// total ~0.03 vs 0.072 threshold). Single K buffer, 1 MFMA per S-subtile.
// All LDS layouts verified conflict-free (<=2-way) under the 8-lane/128B
// phase model: ks rows 80 B (quad advance 5, coprime 8), vs/pb rows 144 B
// (quad advance 9 == 1 mod 8), mask broadcast reads. 37 KB LDS -> 4 blk/CU.

constexpr int cD  = 256;
constexpr int cL  = 1024;
constexpr int cH  = 8;
constexpr int cDK = 32;

typedef _Float16 f16;
typedef __attribute__((ext_vector_type(8))) _Float16 h8;   // 8 f16 = 4 VGPRs
typedef __attribute__((ext_vector_type(4))) _Float16 h4;   // 8 B
typedef __attribute__((ext_vector_type(4))) float f4v;     // MFMA C/D

// ---------------------------------------------------------------------------
// Kernel 1: K -> masked fp16 [b][h][l][c] (A-frag staging layout);
// V -> fp16 [b][h][c][l]. grid 1024 = (b:8, h:8, lt:16 of 64 l), block 256.
// ---------------------------------------------------------------------------
__global__ __launch_bounds__(256, 4) void proj_kv_kernel(
    const float* __restrict__ keys, const float* __restrict__ values,
    const float* __restrict__ mask, const float* __restrict__ Wk,
    const float* __restrict__ Wv, f16* __restrict__ kp_h,
    f16* __restrict__ vp_h)
{
    __shared__ __align__(16) float xs[32][68];
    __shared__ __align__(16) float wT[32][36];
    __shared__ float msl[64];

    const int t   = threadIdx.x;
    const int bid = blockIdx.x;
    const int lt  = bid & 15;
    const int h   = (bid >> 4) & 7;
    const int b   = bid >> 7;
    const int l0  = lt * 64;

    if (t < 64) msl[t] = mask[b * cL + l0 + t];

    // ---------------- K pass ----------------
    for (int idx = t; idx < 512; idx += 256) {
        int j = idx >> 4, l4 = (idx & 15) * 4;
        *reinterpret_cast<float4*>(&xs[j][l4]) =
            *reinterpret_cast<const float4*>(&keys[(b * cD + h * cDK + j) * cL + l0 + l4]);
    }
    for (int idx = t; idx < 1024; idx += 256) {
        int c = idx >> 5, j = idx & 31;
        wT[j][c] = Wk[(h * cDK + c) * cDK + j];
    }
    __syncthreads();
    {
        // lane map: ig = t&3 fast -> K stores are 16B x 64 lanes contiguous
        const int l = t >> 2, ig = t & 3;
        float acc[8] = {0, 0, 0, 0, 0, 0, 0, 0};
        #pragma unroll
        for (int j = 0; j < 32; ++j) {
            float xv = xs[j][l];                     // 4-lane broadcast
            float4 w0 = *reinterpret_cast<const float4*>(&wT[j][ig * 8]);
            float4 w1 = *reinterpret_cast<const float4*>(&wT[j][ig * 8 + 4]);
            acc[0] += w0.x * xv; acc[1] += w0.y * xv;
            acc[2] += w0.z * xv; acc[3] += w0.w * xv;
            acc[4] += w1.x * xv; acc[5] += w1.y * xv;
            acc[6] += w1.z * xv; acc[7] += w1.w * xv;
        }
        float mk = msl[l];
        h8 hv;
        #pragma unroll
        for (int i = 0; i < 8; ++i) hv[i] = (f16)(acc[i] * mk);
        size_t off = (((size_t)(b * cH + h)) * cL + l0 + l) * cDK + ig * 8;
        *reinterpret_cast<h8*>(&kp_h[off]) = hv;
    }
    __syncthreads();

    // ---------------- V pass ----------------
    for (int idx = t; idx < 512; idx += 256) {
        int j = idx >> 4, l4 = (idx & 15) * 4;
        *reinterpret_cast<float4*>(&xs[j][l4]) =
            *reinterpret_cast<const float4*>(&values[(b * cD + h * cDK + j) * cL + l0 + l4]);
    }
    for (int idx = t; idx < 1024; idx += 256) {
        int c = idx >> 5, j = idx & 31;
        wT[j][c] = Wv[(h * cDK + c) * cDK + j];
    }
    __syncthreads();
    {
        const int l4 = (t & 15) * 4;
        const int c0 = (t >> 4) * 2;
        float a0[4] = {0, 0, 0, 0}, a1[4] = {0, 0, 0, 0};
        #pragma unroll
        for (int j = 0; j < 32; ++j) {
            float4 xv = *reinterpret_cast<const float4*>(&xs[j][l4]);
            float w0 = wT[j][c0], w1 = wT[j][c0 + 1];
            a0[0] += w0 * xv.x; a0[1] += w0 * xv.y; a0[2] += w0 * xv.z; a0[3] += w0 * xv.w;
            a1[0] += w1 * xv.x; a1[1] += w1 * xv.y; a1[2] += w1 * xv.z; a1[3] += w1 * xv.w;
        }
        size_t base = ((size_t)(b * cH + h)) * cDK;
        h4 v0, v1;
        #pragma unroll
        for (int i = 0; i < 4; ++i) { v0[i] = (f16)a0[i]; v1[i] = (f16)a1[i]; }
        *reinterpret_cast<h4*>(&vp_h[(base + c0) * cL + l0 + l4])     = v0;
        *reinterpret_cast<h4*>(&vp_h[(base + c0 + 1) * cL + l0 + l4]) = v1;
    }
}

// ---------------------------------------------------------------------------
// Kernel 2: fused attention, fp16 MFMA. Block = (b, h, 64-row strip), 4
// waves; wave w owns rows r = w*16 + ln15 (one row per lane end-to-end).
// grid 1024 = (b:8, h:8, strip:16), block 256.
// ---------------------------------------------------------------------------
__global__ __launch_bounds__(256, 4) void attn_kernel(
    const float* __restrict__ queries, const float* __restrict__ mask,
    const float* __restrict__ Wq, const f16* __restrict__ kp_h,
    const f16* __restrict__ vp_h, f16* __restrict__ val_h)
{
    __shared__ __align__(16) char smem[37888];
    f16*   ks    = (f16*)smem;             // [2][64*40]  10240 B, rows 80 B
    f16*   vsb   = (f16*)(smem + 10240);   // [2][32*72]   9216 B, rows 144 B
    f16*   qsb   = (f16*)(smem + 19456);   // [64*40]      5120 B
    f16*   pbf   = (f16*)(smem + 24576);   // [64*72]      9216 B, rows 144 B
    float* msall = (float*)(smem + 33792); // [1024]       4096 B
    float* qtmp  = (float*)smem;           // scratch [32][68] (dies pre-loop)
    float* wqt   = (float*)(smem + 8704);  // scratch [32][32]

    const int t     = threadIdx.x;
    const int bid   = blockIdx.x;
    const int strip = bid & 15;
    const int h     = (bid >> 4) & 7;
    const int b     = bid >> 7;
    const int r0    = strip * 64;
    const int lane  = t & 63;
    const int w     = t >> 6;
    const int ln15  = lane & 15;
    const int lq    = lane >> 4;

    // ---- prologue: raw q tile, WqT, full mask vector ----
    {
        int j = t >> 3, f8 = (t & 7) * 8;
        const float* src = &queries[(b * cD + h * cDK + j) * cL + r0 + f8];
        float4 v0 = *reinterpret_cast<const float4*>(src);
        float4 v1 = *reinterpret_cast<const float4*>(src + 4);
        *reinterpret_cast<float4*>(&qtmp[j * 68 + f8])     = v0;
        *reinterpret_cast<float4*>(&qtmp[j * 68 + f8 + 4]) = v1;
    }
    {
        int c = t >> 3, j4 = (t & 7) * 4;
        float4 wv = *reinterpret_cast<const float4*>(&Wq[(h * cDK + c) * cDK + j4]);
        wqt[(j4 + 0) * 32 + c] = wv.x; wqt[(j4 + 1) * 32 + c] = wv.y;
        wqt[(j4 + 2) * 32 + c] = wv.z; wqt[(j4 + 3) * 32 + c] = wv.w;
    }
    *reinterpret_cast<float4*>(&msall[t * 4]) =
        *reinterpret_cast<const float4*>(&mask[b * cL + t * 4]);
    __syncthreads();

    // ---- q projection (fp32 accumulate) -> fp16 qsb[r][c], rows 80 B ----
    {
        float acc[8] = {0, 0, 0, 0, 0, 0, 0, 0};
        #pragma unroll
        for (int j = 0; j < 32; ++j) {
            float xv = qtmp[j * 68 + lane];
            float4 w0 = *reinterpret_cast<const float4*>(&wqt[j * 32 + w * 8]);      // bcast
            float4 w1 = *reinterpret_cast<const float4*>(&wqt[j * 32 + w * 8 + 4]);
            acc[0] += w0.x * xv; acc[1] += w0.y * xv;
            acc[2] += w0.z * xv; acc[3] += w0.w * xv;
            acc[4] += w1.x * xv; acc[5] += w1.y * xv;
            acc[6] += w1.z * xv; acc[7] += w1.w * xv;
        }
        h8 hv;
        #pragma unroll
        for (int i = 0; i < 8; ++i) hv[i] = (f16)acc[i];
        *reinterpret_cast<h8*>(&qsb[lane * 40 + w * 8]) = hv;
    }
    __syncthreads();   // scratch dead; qsb published

    const size_t kvbase = ((size_t)(b * cH + h)) * 32768;   // f16 units
    const int se = t >> 2, sb = (t & 3) * 8;                // K staging coords
    const int vc = t >> 3, veb = (t & 7) * 8;               // V staging coords

    // ---- stage tile 0 into buf 0 ----
    {
        h8 kh = *reinterpret_cast<const h8*>(&kp_h[kvbase + se * 32 + sb]);
        *reinterpret_cast<h8*>(&ks[se * 40 + sb]) = kh;
        h8 vv = *reinterpret_cast<const h8*>(&vp_h[kvbase + vc * 1024 + veb]);
        *reinterpret_cast<h8*>(&vsb[vc * 72 + veb]) = vv;
    }

    // ---- persistent B-frag: q row of this lane ----
    const h8 qf = *reinterpret_cast<const h8*>(&qsb[(w * 16 + ln15) * 40 + lq * 8]);

    f4v o0 = {0.f, 0.f, 0.f, 0.f}, o1 = {0.f, 0.f, 0.f, 0.f};
    float mo = -INFINITY, lr = 0.f;
    const int prow  = (w * 16 + ln15) * 72;
    const int vsoff = ln15 * 72 + lq * 8;

    for (int et = 0; et < 16; ++et) {
        __syncthreads();        // tile et visible in buf pp
        const int pp = et & 1;
        const bool pre = (et < 15);
        h8 khp, vvp;
        if (pre) {              // early global loads for tile et+1
            const int e0n = (et + 1) * 64;
            khp = *reinterpret_cast<const h8*>(&kp_h[kvbase + (e0n + se) * 32 + sb]);
            vvp = *reinterpret_cast<const h8*>(&vp_h[kvbase + vc * 1024 + e0n + veb]);
        }

        // ---- S^T tiles: D[e][r] = K[e][c] x Q^T[c][r] ----
        f4v sA[4];
        #pragma unroll
        for (int es = 0; es < 4; ++es) {
            const h8 kf = *reinterpret_cast<const h8*>(
                &ks[pp * 2560 + (es * 16 + ln15) * 40 + lq * 8]);
            f4v z = {0.f, 0.f, 0.f, 0.f};
            sA[es] = __builtin_amdgcn_mfma_f32_16x16x32_f16(kf, qf, z, 0, 0, 0);
        }

        // ---- softmax: lane owns row r = w*16+ln15 (scalar stats) ----
        float tm = fmaxf(fmaxf(fmaxf(sA[0][0], sA[0][1]), fmaxf(sA[0][2], sA[0][3])),
                   fmaxf(fmaxf(fmaxf(sA[1][0], sA[1][1]), fmaxf(sA[1][2], sA[1][3])),
                   fmaxf(fmaxf(fmaxf(sA[2][0], sA[2][1]), fmaxf(sA[2][2], sA[2][3])),
                         fmaxf(fmaxf(sA[3][0], sA[3][1]), fmaxf(sA[3][2], sA[3][3])))));
        tm = fmaxf(tm, __shfl_xor(tm, 16));
        tm = fmaxf(tm, __shfl_xor(tm, 32));
        const float mn = fmaxf(mo, tm);
        const float al = __expf(mo - mn);     // first tile: exp(-inf) = 0
        mo = mn;
        o0[0] *= al; o0[1] *= al; o0[2] *= al; o0[3] *= al;
        o1[0] *= al; o1[1] *= al; o1[2] *= al; o1[3] *= al;

        float ps = 0.f;
        #pragma unroll
        for (int es = 0; es < 4; ++es) {
            // broadcast read: all ln15 share this address
            float4 mk4 = *reinterpret_cast<const float4*>(&msall[et * 64 + es * 16 + lq * 4]);
            float p0 = __expf((sA[es][0] - mn) * mk4.x) * mk4.x;
            float p1 = __expf((sA[es][1] - mn) * mk4.y) * mk4.y;
            float p2 = __expf((sA[es][2] - mn) * mk4.z) * mk4.z;
            float p3 = __expf((sA[es][3] - mn) * mk4.w) * mk4.w;
            ps += (p0 + p1) + (p2 + p3);
            h4 pk; pk[0] = (f16)p0; pk[1] = (f16)p1; pk[2] = (f16)p2; pk[3] = (f16)p3;
            *reinterpret_cast<h4*>(&pbf[prow + es * 16 + lq * 4]) = pk;  // wave-private
        }
        ps += __shfl_xor(ps, 16);
        ps += __shfl_xor(ps, 32);
        lr = lr * al + ps;

        // ---- PV: o^T[c][r] += V[c][e] x P^T[e][r] (same-wave DS order) ----
        #pragma unroll
        for (int ch = 0; ch < 2; ++ch) {
            h8 pf  = *reinterpret_cast<const h8*>(&pbf[prow + ch * 32 + lq * 8]);
            h8 va0 = *reinterpret_cast<const h8*>(&vsb[pp * 2304 + vsoff + ch * 32]);
            h8 va1 = *reinterpret_cast<const h8*>(&vsb[pp * 2304 + vsoff + ch * 32 + 1152]);
            o0 = __builtin_amdgcn_mfma_f32_16x16x32_f16(va0, pf, o0, 0, 0, 0);
            o1 = __builtin_amdgcn_mfma_f32_16x16x32_f16(va1, pf, o1, 0, 0, 0);
        }

        // ---- late LDS writes: publish tile et+1 into buf pp^1 ----
        if (pre) {
            *reinterpret_cast<h8*>(&ks[(pp ^ 1) * 2560 + se * 40 + sb]) = khp;
            *reinterpret_cast<h8*>(&vsb[(pp ^ 1) * 2304 + vc * 72 + veb]) = vvp;
        }
    }

    // ---- epilogue: val_h[b][l=r][h*32+c] = fp16(o / (l + eps)) ----
    {
        const float linv = 1.0f / (lr + 1e-8f);
        const size_t obase = ((size_t)(b * cL + r0 + w * 16 + ln15)) * cD + h * cDK;
        h4 q0, q1;
        #pragma unroll
        for (int i = 0; i < 4; ++i) {
            q0[i] = (f16)(o0[i] * linv);
            q1[i] = (f16)(o1[i] * linv);
        }
        *reinterpret_cast<h4*>(&val_h[obase + lq * 4])      = q0;
        *reinterpret_cast<h4*>(&val_h[obase + 16 + lq * 4]) = q1;
    }
}

// ---------------------------------------------------------------------------
// Kernel 3: out[b][l][i] = mask[b][l] * (sum_j Wp[i][j]*val[b][l][j] + bp[i])
// fp16 MFMA. grid 512 = (b:8, lt:16 of 64 l, it:4 of 64 i), block 256.
// ---------------------------------------------------------------------------
__global__ __launch_bounds__(256, 2) void outproj_kernel(
    const f16* __restrict__ val_h, const float* __restrict__ Wp,
    const float* __restrict__ bp, const float* __restrict__ mask,
    float* __restrict__ out)
{
    __shared__ __align__(16) f16 vt[64 * 264];    // [64 l][264 j-pad] rows 528 B
    __shared__ __align__(16) f16 wpb[64 * 264];   // [64 i][264 j-pad]
    __shared__ float mrow[64];

    const int t    = threadIdx.x;
    const int bid  = blockIdx.x;
    const int it   = bid & 3;
    const int lt   = (bid >> 2) & 15;
    const int b    = bid >> 6;
    const int l0   = lt * 64, i0 = it * 64;
    const int lane = t & 63, w = t >> 6, ln15 = lane & 15, lq = lane >> 4;

    {   // stage val tile; row = t&63 fast -> conflict-free LDS writes
        int row = t & 63, seg = (t >> 6) * 64;
        const f16* src = &val_h[((size_t)(b * cL + l0 + row)) * cD + seg];
        #pragma unroll
        for (int k = 0; k < 8; ++k)
            *reinterpret_cast<h8*>(&vt[row * 264 + seg + k * 8]) =
                *reinterpret_cast<const h8*>(src + k * 8);
    }
    {   // stage Wp tile (fp32 -> fp16)
        int row = t & 63, seg = (t >> 6) * 64;
        const float* src = &Wp[((size_t)(i0 + row)) * cD + seg];
        #pragma unroll
        for (int k = 0; k < 8; ++k) {
            float4 f0 = *reinterpret_cast<const float4*>(src + k * 8);
            float4 f1 = *reinterpret_cast<const float4*>(src + k * 8 + 4);
            h8 hv;
            hv[0] = (f16)f0.x; hv[1] = (f16)f0.y; hv[2] = (f16)f0.z; hv[3] = (f16)f0.w;
            hv[4] = (f16)f1.x; hv[5] = (f16)f1.y; hv[6] = (f16)f1.z; hv[7] = (f16)f1.w;
            *reinterpret_cast<h8*>(&wpb[row * 264 + seg + k * 8]) = hv;
        }
    }
    if (t < 64) mrow[t] = mask[b * cL + l0 + t];
    __syncthreads();

    f4v acc[4] = {{0.f, 0.f, 0.f, 0.f}, {0.f, 0.f, 0.f, 0.f},
                  {0.f, 0.f, 0.f, 0.f}, {0.f, 0.f, 0.f, 0.f}};
    #pragma unroll
    for (int kc = 0; kc < 8; ++kc) {
        h8 aA = *reinterpret_cast<const h8*>(&vt[(w * 16 + ln15) * 264 + kc * 32 + lq * 8]);
        #pragma unroll
        for (int ti = 0; ti < 4; ++ti) {
            h8 bB = *reinterpret_cast<const h8*>(&wpb[(ti * 16 + ln15) * 264 + kc * 32 + lq * 8]);
            acc[ti] = __builtin_amdgcn_mfma_f32_16x16x32_f16(aA, bB, acc[ti], 0, 0, 0);
        }
    }

    float mk[4];
    #pragma unroll
    for (int rg = 0; rg < 4; ++rg) mk[rg] = mrow[w * 16 + lq * 4 + rg];
    #pragma unroll
    for (int ti = 0; ti < 4; ++ti) {
        float bpv = bp[i0 + ti * 16 + ln15];
        #pragma unroll
        for (int rg = 0; rg < 4; ++rg) {
            int l = l0 + w * 16 + lq * 4 + rg;
            out[((size_t)(b * cL + l)) * cD + i0 + ti * 16 + ln15] =
                (acc[ti][rg] + bpv) * mk[rg];
        }
    }
}

// ---------------------------------------------------------------------------
extern "C" void kernel_launch(void* const* d_in, const int* in_sizes, int n_in,
                              void* d_out, int out_size, void* d_ws, size_t ws_size,
                              hipStream_t stream) {
    const float* queries = (const float*)d_in[0];
    const float* keys    = (const float*)d_in[1];
    const float* values  = (const float*)d_in[2];
    const float* mask    = (const float*)d_in[3];
    const float* Wq      = (const float*)d_in[4];
    const float* Wk      = (const float*)d_in[5];
    const float* Wv      = (const float*)d_in[6];
    const float* Wp      = (const float*)d_in[7];
    const float* bp      = (const float*)d_in[8];
    float* out = (float*)d_out;

    // ws: kp_h 4MB | vp_h 4MB | val_h 4MB  (12 MB)
    char* wsb = (char*)d_ws;
    f16* kp_h  = (f16*)(wsb);
    f16* vp_h  = (f16*)(wsb + (4u << 20));
    f16* val_h = (f16*)(wsb + (8u << 20));

    proj_kv_kernel<<<dim3(1024), dim3(256), 0, stream>>>(keys, values, mask, Wk, Wv,
                                                         kp_h, vp_h);
    attn_kernel<<<dim3(1024), dim3(256), 0, stream>>>(queries, mask, Wq,
                                                      kp_h, vp_h, val_h);
    outproj_kernel<<<dim3(512), dim3(256), 0, stream>>>(val_h, Wp, bp, mask, out);
}